// Round 1
// baseline (2747.408 us; speedup 1.0000x reference)
//
#include <hip/hip_runtime.h>
#include <hip/hip_bf16.h>
#include <math.h>

#define NBATCH 64
#define TSEQ   1000
#define DIN    257
#define HID    128
#define GATES  512   // 4*HID

// ---------------------------------------------------------------------------
// Generic tiled fp32 GEMM: C[M,Ncols] = act(A[M,K] @ W[Ncols,K]^T + b1 (+b2))
// 64x64 tile per 256-thread block, 4x4 per thread, K-chunks of 16 via LDS.
// ACT: 0 = identity, 1 = sigmoid.
// ---------------------------------------------------------------------------
template<int ACT>
__global__ __launch_bounds__(256) void gemm_bt(
    const float* __restrict__ A, const float* __restrict__ W,
    const float* __restrict__ b1, const float* __restrict__ b2,
    float* __restrict__ C, int M, int K, int Ncols)
{
    // k-major LDS tiles: [k][row], padded to 68 to break power-of-2 strides
    __shared__ float As[16][68];
    __shared__ float Ws[16][68];
    const int tid = threadIdx.x;
    const int tx  = tid & 15;    // col group (4 cols each)
    const int ty  = tid >> 4;    // row group (4 rows each)
    const int m0  = blockIdx.y * 64;
    const int n0  = blockIdx.x * 64;

    float acc[4][4];
#pragma unroll
    for (int i = 0; i < 4; ++i)
#pragma unroll
        for (int j = 0; j < 4; ++j) acc[i][j] = 0.f;

    for (int kc = 0; kc < K; kc += 16) {
        const int kk = tid & 15;     // k within chunk
        const int r0 = tid >> 4;     // row 0..15, step 16
#pragma unroll
        for (int rr = 0; rr < 64; rr += 16) {
            const int r  = r0 + rr;
            const int kg = kc + kk;
            float av = 0.f, wv = 0.f;
            if (kg < K) {
                av = A[(size_t)(m0 + r) * K + kg];
                const int wn = n0 + r;
                if (wn < Ncols) wv = W[(size_t)wn * K + kg];
            }
            As[kk][r] = av;
            Ws[kk][r] = wv;
        }
        __syncthreads();
#pragma unroll
        for (int k = 0; k < 16; ++k) {
            const float4 av4 = *(const float4*)&As[k][ty * 4];
            const float4 bv4 = *(const float4*)&Ws[k][tx * 4];
            const float a4[4] = {av4.x, av4.y, av4.z, av4.w};
            const float b4[4] = {bv4.x, bv4.y, bv4.z, bv4.w};
#pragma unroll
            for (int i = 0; i < 4; ++i)
#pragma unroll
                for (int j = 0; j < 4; ++j)
                    acc[i][j] += a4[i] * b4[j];
        }
        __syncthreads();
    }

#pragma unroll
    for (int i = 0; i < 4; ++i) {
        const int m = m0 + ty * 4 + i;
#pragma unroll
        for (int j = 0; j < 4; ++j) {
            const int col = n0 + tx * 4 + j;
            if (col < Ncols) {
                float v = acc[i][j] + b1[col] + (b2 ? b2[col] : 0.f);
                if (ACT == 1) v = 1.f / (1.f + __expf(-v));
                C[(size_t)m * Ncols + col] = v;
            }
        }
    }
}

// ---------------------------------------------------------------------------
// LSTM recurrence for one layer. One block per batch element (64 blocks),
// 512 threads = one gate per thread. Whh row for gate g lives in 128 VGPRs.
// pre: [N,T,512] precomputed x@Wih^T + bih + bhh. hseq: [N,T,128] output h_t.
// states layout [256,128]: rows h_row0+n = h, h_row0+64+n = c.
// ---------------------------------------------------------------------------
__global__ __launch_bounds__(512, 2) void lstm_rec(
    const float* __restrict__ pre, const float* __restrict__ states_in,
    const float* __restrict__ Whh, float* __restrict__ hseq,
    float* __restrict__ states_out, int h_row0)
{
    const int n = blockIdx.x;      // batch element
    const int g = threadIdx.x;     // gate index 0..511 (i:0-127 f:128-255 g:256-383 o:384-511)

    __shared__ float h_s[HID];
    __shared__ float c_s[HID];
    __shared__ float gates[GATES];

    // Whh row for this gate -> registers (128 VGPRs)
    float w[HID];
    const float* wrow = Whh + (size_t)g * HID;
#pragma unroll
    for (int k = 0; k < HID; k += 4) {
        const float4 t = *(const float4*)(wrow + k);
        w[k + 0] = t.x; w[k + 1] = t.y; w[k + 2] = t.z; w[k + 3] = t.w;
    }

    if (g < HID) {
        h_s[g] = states_in[(size_t)(h_row0 + n) * HID + g];
        c_s[g] = states_in[(size_t)(h_row0 + 64 + n) * HID + g];
    }
    __syncthreads();

    const float* pre_n = pre + (size_t)n * TSEQ * GATES;
    float pre_cur = pre_n[g];
    float pre_nxt = pre_n[GATES + g];

    for (int t = 0; t < TSEQ; ++t) {
        const float pre_t = pre_cur;
        pre_cur = pre_nxt;
        if (t + 2 < TSEQ) pre_nxt = pre_n[(size_t)(t + 2) * GATES + g];

        // gate pre-activation: pre + dot(h, Whh[g,:])
        float acc = pre_t;
        const float4* h4 = (const float4*)h_s;
#pragma unroll
        for (int k4 = 0; k4 < HID / 4; ++k4) {
            const float4 hv = h4[k4];
            acc += hv.x * w[4 * k4 + 0];
            acc += hv.y * w[4 * k4 + 1];
            acc += hv.z * w[4 * k4 + 2];
            acc += hv.w * w[4 * k4 + 3];
        }

        // activation: gates 256..383 (cell input) use tanh, others sigmoid.
        // g>>7 is wave-uniform (waves 4,5 are exactly type 2) -> no divergence.
        float a;
        if ((g >> 7) == 2) a = tanhf(acc);
        else               a = 1.f / (1.f + __expf(-acc));
        gates[g] = a;
        __syncthreads();

        if (g < HID) {
            const float i_ = gates[g];
            const float f_ = gates[HID + g];
            const float g_ = gates[2 * HID + g];
            const float o_ = gates[3 * HID + g];
            const float c  = f_ * c_s[g] + i_ * g_;
            const float hh = o_ * tanhf(c);
            c_s[g] = c;
            h_s[g] = hh;
            hseq[((size_t)n * TSEQ + t) * HID + g] = hh;
            if (t == TSEQ - 1) {
                states_out[(size_t)(h_row0 + n) * HID + g]      = hh;
                states_out[(size_t)(h_row0 + 64 + n) * HID + g] = c;
            }
        }
        __syncthreads();
    }
}

// ---------------------------------------------------------------------------
extern "C" void kernel_launch(void* const* d_in, const int* in_sizes, int n_in,
                              void* d_out, int out_size, void* d_ws, size_t ws_size,
                              hipStream_t stream)
{
    const float* x     = (const float*)d_in[0];   // [64,1000,257]
    const float* st_in = (const float*)d_in[1];   // [1,256,128]
    const float* Wih1  = (const float*)d_in[2];   // [512,257]
    const float* Whh1  = (const float*)d_in[3];   // [512,128]
    const float* bih1  = (const float*)d_in[4];   // [512]
    const float* bhh1  = (const float*)d_in[5];   // [512]
    const float* Wih2  = (const float*)d_in[6];   // [512,128]
    const float* Whh2  = (const float*)d_in[7];   // [512,128]
    const float* bih2  = (const float*)d_in[8];   // [512]
    const float* bhh2  = (const float*)d_in[9];   // [512]
    const float* Wd    = (const float*)d_in[10];  // [257,128]
    const float* bd    = (const float*)d_in[11];  // [257]

    float* out_mask   = (float*)d_out;                                // [64,1000,257]
    float* out_states = (float*)d_out + (size_t)NBATCH * TSEQ * DIN;  // [256,128]

    const int M = NBATCH * TSEQ;  // 64000
    float* bufA = (float*)d_ws;                       // [M,512] pre1 / pre2 (131 MB)
    float* bufB = bufA + (size_t)M * GATES;           // [M,128] h1seq / x2 (32.8 MB)

    // K1: pre1 = x @ Wih1^T + bih1 + bhh1
    gemm_bt<0><<<dim3(GATES / 64, M / 64), 256, 0, stream>>>(
        x, Wih1, bih1, bhh1, bufA, M, DIN, GATES);

    // K2: layer-1 recurrence -> h1seq (bufB), final h1/c1 -> out_states rows 0..127
    lstm_rec<<<NBATCH, GATES, 0, stream>>>(bufA, st_in, Whh1, bufB, out_states, 0);

    // K3: pre2 = h1seq @ Wih2^T + bih2 + bhh2 (overwrites bufA)
    gemm_bt<0><<<dim3(GATES / 64, M / 64), 256, 0, stream>>>(
        bufB, Wih2, bih2, bhh2, bufA, M, HID, GATES);

    // K4: layer-2 recurrence -> x2 (bufB, h1seq dead), h2/c2 -> out_states rows 128..255
    lstm_rec<<<NBATCH, GATES, 0, stream>>>(bufA, st_in, Whh2, bufB, out_states, 128);

    // K5: mask = sigmoid(x2 @ Wd^T + bd) -> d_out
    gemm_bt<1><<<dim3((DIN + 63) / 64, M / 64), 256, 0, stream>>>(
        bufB, Wd, bd, nullptr, out_mask, M, HID, DIN);
}

// Round 2
// 1763.318 us; speedup vs baseline: 1.5581x; 1.5581x over previous
//
#include <hip/hip_runtime.h>
#include <hip/hip_bf16.h>
#include <math.h>

#define NBATCH 64
#define TSEQ   1000
#define DIN    257
#define HID    128
#define GATES  512   // 4*HID

typedef _Float16 h2 __attribute__((ext_vector_type(2)));

__device__ __forceinline__ float fast_sigmoid(float x) {
    return __builtin_amdgcn_rcpf(1.f + __expf(-x));
}
__device__ __forceinline__ float fast_tanh(float x) {
    const float ax = fabsf(x);
    const float e  = __expf(2.f * ax);            // large -> inf -> rcp -> 0 -> t=1 (safe)
    const float t  = 1.f - 2.f * __builtin_amdgcn_rcpf(e + 1.f);
    return copysignf(t, x);
}

// ---------------------------------------------------------------------------
// Generic tiled fp32 GEMM: C[M,Ncols] = act(A[M,K] @ W[Ncols,K]^T + b1 (+b2))
// 64x64 tile per 256-thread block, 4x4 per thread, K-chunks of 16 via LDS.
// ACT: 0 = identity, 1 = sigmoid.  (unchanged from R1 — isolate lstm change)
// ---------------------------------------------------------------------------
template<int ACT>
__global__ __launch_bounds__(256) void gemm_bt(
    const float* __restrict__ A, const float* __restrict__ W,
    const float* __restrict__ b1, const float* __restrict__ b2,
    float* __restrict__ C, int M, int K, int Ncols)
{
    __shared__ float As[16][68];
    __shared__ float Ws[16][68];
    const int tid = threadIdx.x;
    const int tx  = tid & 15;
    const int ty  = tid >> 4;
    const int m0  = blockIdx.y * 64;
    const int n0  = blockIdx.x * 64;

    float acc[4][4];
#pragma unroll
    for (int i = 0; i < 4; ++i)
#pragma unroll
        for (int j = 0; j < 4; ++j) acc[i][j] = 0.f;

    for (int kc = 0; kc < K; kc += 16) {
        const int kk = tid & 15;
        const int r0 = tid >> 4;
#pragma unroll
        for (int rr = 0; rr < 64; rr += 16) {
            const int r  = r0 + rr;
            const int kg = kc + kk;
            float av = 0.f, wv = 0.f;
            if (kg < K) {
                av = A[(size_t)(m0 + r) * K + kg];
                const int wn = n0 + r;
                if (wn < Ncols) wv = W[(size_t)wn * K + kg];
            }
            As[kk][r] = av;
            Ws[kk][r] = wv;
        }
        __syncthreads();
#pragma unroll
        for (int k = 0; k < 16; ++k) {
            const float4 av4 = *(const float4*)&As[k][ty * 4];
            const float4 bv4 = *(const float4*)&Ws[k][tx * 4];
            const float a4[4] = {av4.x, av4.y, av4.z, av4.w};
            const float b4[4] = {bv4.x, bv4.y, bv4.z, bv4.w};
#pragma unroll
            for (int i = 0; i < 4; ++i)
#pragma unroll
                for (int j = 0; j < 4; ++j)
                    acc[i][j] += a4[i] * b4[j];
        }
        __syncthreads();
    }

#pragma unroll
    for (int i = 0; i < 4; ++i) {
        const int m = m0 + ty * 4 + i;
#pragma unroll
        for (int j = 0; j < 4; ++j) {
            const int col = n0 + tx * 4 + j;
            if (col < Ncols) {
                float v = acc[i][j] + b1[col] + (b2 ? b2[col] : 0.f);
                if (ACT == 1) v = 1.f / (1.f + __expf(-v));
                C[(size_t)m * Ncols + col] = v;
            }
        }
    }
}

// ---------------------------------------------------------------------------
// LSTM recurrence. One block per batch element (64 blocks), 512 threads = one
// gate per thread. Whh row held as 64 packed f16x2 VGPRs; h broadcast from LDS
// as f16 pairs; recurrent dot via v_dot2_f32_f16 with 4 independent
// accumulator chains. c lives in a register of its owner thread.
// ---------------------------------------------------------------------------
__global__ __launch_bounds__(512, 2) void lstm_rec(
    const float* __restrict__ pre, const float* __restrict__ states_in,
    const float* __restrict__ Whh, float* __restrict__ hseq,
    float* __restrict__ states_out, int h_row0)
{
    const int n = blockIdx.x;
    const int g = threadIdx.x;   // i:0-127 f:128-255 g:256-383 o:384-511

    __shared__ __align__(16) _Float16 h_h[HID];   // h_t as f16, broadcast source
    __shared__ float gates[GATES];

    // Whh row -> 64 packed f16x2 registers
    h2 w[HID / 2];
    {
        const float4* wrow4 = (const float4*)(Whh + (size_t)g * HID);
#pragma unroll
        for (int k4 = 0; k4 < HID / 4; ++k4) {
            const float4 t = wrow4[k4];
            w[2 * k4 + 0] = h2{(_Float16)t.x, (_Float16)t.y};
            w[2 * k4 + 1] = h2{(_Float16)t.z, (_Float16)t.w};
        }
    }

    float c_r = 0.f;   // cell state, owner-thread register (g < HID only)
    if (g < HID) {
        const float h0 = states_in[(size_t)(h_row0 + n) * HID + g];
        c_r = states_in[(size_t)(h_row0 + 64 + n) * HID + g];
        h_h[g] = (_Float16)h0;
    }
    __syncthreads();

    const float* pre_n = pre + (size_t)n * TSEQ * GATES;
    float pre_cur = pre_n[g];
    float pre_nxt = pre_n[GATES + g];

    for (int t = 0; t < TSEQ; ++t) {
        const float pre_t = pre_cur;
        pre_cur = pre_nxt;
        if (t + 2 < TSEQ) pre_nxt = pre_n[(size_t)(t + 2) * GATES + g];

        // gate pre-activation: pre + dot(h, Whh[g,:]) -- f16 dot2, 4 chains
        float a0 = 0.f, a1 = 0.f, a2 = 0.f, a3 = 0.f;
        const uint4* hp = (const uint4*)h_h;   // 16 x uint4 = 128 halves
#if __has_builtin(__builtin_amdgcn_fdot2)
#pragma unroll
        for (int j = 0; j < HID / 8; ++j) {    // 16 iters, 4 dot2 each
            const uint4 hv = hp[j];
            a0 = __builtin_amdgcn_fdot2(w[4 * j + 0], __builtin_bit_cast(h2, hv.x), a0, false);
            a1 = __builtin_amdgcn_fdot2(w[4 * j + 1], __builtin_bit_cast(h2, hv.y), a1, false);
            a2 = __builtin_amdgcn_fdot2(w[4 * j + 2], __builtin_bit_cast(h2, hv.z), a2, false);
            a3 = __builtin_amdgcn_fdot2(w[4 * j + 3], __builtin_bit_cast(h2, hv.w), a3, false);
        }
#else
#pragma unroll
        for (int j = 0; j < HID / 8; ++j) {
            const uint4 hv = hp[j];
            const h2 h0 = __builtin_bit_cast(h2, hv.x);
            const h2 h1 = __builtin_bit_cast(h2, hv.y);
            const h2 h2v = __builtin_bit_cast(h2, hv.z);
            const h2 h3 = __builtin_bit_cast(h2, hv.w);
            a0 += (float)w[4 * j + 0].x * (float)h0.x + (float)w[4 * j + 0].y * (float)h0.y;
            a1 += (float)w[4 * j + 1].x * (float)h1.x + (float)w[4 * j + 1].y * (float)h1.y;
            a2 += (float)w[4 * j + 2].x * (float)h2v.x + (float)w[4 * j + 2].y * (float)h2v.y;
            a3 += (float)w[4 * j + 3].x * (float)h3.x + (float)w[4 * j + 3].y * (float)h3.y;
        }
#endif
        const float acc = pre_t + ((a0 + a1) + (a2 + a3));

        // wave-uniform activation select: waves 4,5 (threads 256-383) are tanh
        float a;
        if ((g >> 7) == 2) a = fast_tanh(acc);
        else               a = fast_sigmoid(acc);
        gates[g] = a;
        __syncthreads();

        if (g < HID) {
            const float i_ = gates[g];
            const float f_ = gates[HID + g];
            const float g_ = gates[2 * HID + g];
            const float o_ = gates[3 * HID + g];
            const float c  = f_ * c_r + i_ * g_;
            const float hh = o_ * fast_tanh(c);
            c_r = c;
            h_h[g] = (_Float16)hh;
            hseq[((size_t)n * TSEQ + t) * HID + g] = hh;
            if (t == TSEQ - 1) {
                states_out[(size_t)(h_row0 + n) * HID + g]      = hh;
                states_out[(size_t)(h_row0 + 64 + n) * HID + g] = c;
            }
        }
        __syncthreads();
    }
}

// ---------------------------------------------------------------------------
extern "C" void kernel_launch(void* const* d_in, const int* in_sizes, int n_in,
                              void* d_out, int out_size, void* d_ws, size_t ws_size,
                              hipStream_t stream)
{
    const float* x     = (const float*)d_in[0];
    const float* st_in = (const float*)d_in[1];
    const float* Wih1  = (const float*)d_in[2];
    const float* Whh1  = (const float*)d_in[3];
    const float* bih1  = (const float*)d_in[4];
    const float* bhh1  = (const float*)d_in[5];
    const float* Wih2  = (const float*)d_in[6];
    const float* Whh2  = (const float*)d_in[7];
    const float* bih2  = (const float*)d_in[8];
    const float* bhh2  = (const float*)d_in[9];
    const float* Wd    = (const float*)d_in[10];
    const float* bd    = (const float*)d_in[11];

    float* out_mask   = (float*)d_out;
    float* out_states = (float*)d_out + (size_t)NBATCH * TSEQ * DIN;

    const int M = NBATCH * TSEQ;
    float* bufA = (float*)d_ws;               // [M,512] pre1 / pre2
    float* bufB = bufA + (size_t)M * GATES;   // [M,128] h1seq / x2

    gemm_bt<0><<<dim3(GATES / 64, M / 64), 256, 0, stream>>>(
        x, Wih1, bih1, bhh1, bufA, M, DIN, GATES);

    lstm_rec<<<NBATCH, GATES, 0, stream>>>(bufA, st_in, Whh1, bufB, out_states, 0);

    gemm_bt<0><<<dim3(GATES / 64, M / 64), 256, 0, stream>>>(
        bufB, Wih2, bih2, bhh2, bufA, M, HID, GATES);

    lstm_rec<<<NBATCH, GATES, 0, stream>>>(bufA, st_in, Whh2, bufB, out_states, 128);

    gemm_bt<1><<<dim3((DIN + 63) / 64, M / 64), 256, 0, stream>>>(
        bufB, Wd, bd, nullptr, out_mask, M, HID, DIN);
}